// Round 12
// baseline (1043.793 us; speedup 1.0000x reference)
//
#include <hip/hip_runtime.h>

#define NN 100000
#define NE 600000

typedef unsigned short u16;
typedef float f32x4 __attribute__((ext_vector_type(4)));
typedef short s16x8 __attribute__((ext_vector_type(8)));

__device__ inline u16 f2bf(float f) {            // fp32 -> bf16 RNE
    unsigned u = __float_as_uint(f);
    return (u16)((u + 0x7FFFu + ((u >> 16) & 1u)) >> 16);
}
__device__ inline float bflo(unsigned u) { return __uint_as_float(u << 16); }
__device__ inline float bfhi(unsigned u) { return __uint_as_float(u & 0xFFFF0000u); }
__device__ inline unsigned pk(float a, float b) {
    return (unsigned)f2bf(a) | ((unsigned)f2bf(b) << 16);
}

// ---------------- degree / CSR build + degree-sort ----------------

__global__ void k_init_deg(int* __restrict__ deg, int* __restrict__ hist, int n) {
    int i = blockIdx.x * 256 + threadIdx.x;
    if (i < n) deg[i] = 0;
    if (blockIdx.x == 0 && threadIdx.x < 64) hist[threadIdx.x] = 0;
}

__global__ void k_deg_count(const int* __restrict__ col, int* __restrict__ deg, int E) {
    int e = blockIdx.x * 256 + threadIdx.x;
    if (e < E) atomicAdd(&deg[col[e]], 1);
}

// scan1: per-block exclusive scan of deg; also dinv + degree histogram (fused)
__global__ void k_scan1(const int* __restrict__ deg, int* __restrict__ offs,
                        int* __restrict__ bsums, float* __restrict__ dinv,
                        int* __restrict__ hist, int n) {
    __shared__ int s[256];
    int t = threadIdx.x;
    int i = blockIdx.x * 256 + t;
    int v = (i < n) ? deg[i] : 0;
    if (i < n) {
        dinv[i] = rsqrtf((float)(v + 1));          // +1: self-loop
        atomicAdd(&hist[v < 63 ? v : 63], 1);      // degree histogram (64 bins)
    }
    s[t] = v;
    __syncthreads();
    for (int off = 1; off < 256; off <<= 1) {
        int x = (t >= off) ? s[t - off] : 0;
        __syncthreads();
        s[t] += x;
        __syncthreads();
    }
    if (i < n) offs[i] = s[t] - v;
    if (t == 255) bsums[blockIdx.x] = s[255];
}

__global__ void k_scan2(int* __restrict__ bsums, int nb) {
    __shared__ int s[512];
    int t = threadIdx.x;
    int v = (t < nb) ? bsums[t] : 0;
    s[t] = v;
    __syncthreads();
    for (int off = 1; off < 512; off <<= 1) {
        int x = (t >= off) ? s[t - off] : 0;
        __syncthreads();
        s[t] += x;
        __syncthreads();
    }
    if (t < nb) bsums[t] = s[t] - v;
}

__global__ void k_scan3(int* __restrict__ offs, const int* __restrict__ bsums,
                        int* __restrict__ cursor, int n) {
    int i = blockIdx.x * 256 + threadIdx.x;
    if (i < n) {
        int o = offs[i] + bsums[i >> 8];
        offs[i] = o;
        cursor[i] = o;
    }
}

__global__ void k_fill(const int* __restrict__ row, const int* __restrict__ col,
                       int* __restrict__ cursor, int* __restrict__ srcs, int E) {
    int e = blockIdx.x * 256 + threadIdx.x;
    if (e < E) {
        int p = atomicAdd(&cursor[col[e]], 1);
        srcs[p] = row[e];
    }
}

// exclusive scan of the 64 degree bins -> bin cursors (single block, 64 threads)
__global__ void k_scan_bins(const int* __restrict__ hist, int* __restrict__ bcur) {
    __shared__ int s[64];
    int t = threadIdx.x;
    int v = hist[t];
    s[t] = v;
    __syncthreads();
    for (int off = 1; off < 64; off <<= 1) {
        int x = (t >= off) ? s[t - off] : 0;
        __syncthreads();
        s[t] += x;
        __syncthreads();
    }
    bcur[t] = s[t] - v;
}

// scatter nodes into degree-sorted order (aggs process order[]; waves get
// uniform-degree nodes -> no divergence tail from max(deg of 4))
__global__ void k_scatter_nodes(const int* __restrict__ deg, int* __restrict__ bcur,
                                int* __restrict__ order, int n) {
    int i = blockIdx.x * 256 + threadIdx.x;
    if (i < n) {
        int b = deg[i]; b = b < 63 ? b : 63;
        order[atomicAdd(&bcur[b], 1)] = i;
    }
}

// ---------------- W pack (all 3 weights, one launch) -------------------------
// Wp element ((t*4+kk)*64 + l)*8 + i  <-  W[kk*32 + (l>>4)*8 + i][t*16 + (l&15)]

__device__ inline void pack_one(const float* W, u16* Wp, int g, int DOUT) {
    int i  = g & 7;
    int l  = (g >> 3) & 63;
    int kk = (g >> 9) & 3;
    int t  = g >> 11;
    int k = kk * 32 + ((l >> 4) << 3) + i;
    int c = t * 16 + (l & 15);
    Wp[g] = f2bf(W[k * DOUT + c]);
}

__global__ __launch_bounds__(256)
void k_pack_all(const float* __restrict__ W1, const float* __restrict__ W2,
                const float* __restrict__ W3, u16* __restrict__ wp1,
                u16* __restrict__ wp2, u16* __restrict__ wp3) {
    int gid = blockIdx.x * 256 + threadIdx.x;
    if (gid < 16384) pack_one(W1, wp1, gid, 128);
    else if (gid < 32768) pack_one(W2, wp2, gid - 16384, 128);
    else if (gid < 40960) pack_one(W3, wp3, gid - 32768, 64);
}

// ---------------- GEMM: G = (H @ W) * dinv[row], bf16 MFMA, LDS-free ---------
// Block = 4 waves x 32 rows = 128 rows; each wave's 2 row-groups share B-frags
// (halves B reads and block count vs 16 rows/wave).
// A-frag (16x16x32): lane l holds A[l&15][(l>>4)*8 + i].
// D: col=l&15, row=(l>>4)*4+reg  (guide §3, m89-verified).

template <int DOUT, bool OB16, bool AF32>
__global__ __launch_bounds__(256)
void k_gemm_mfma(const void* __restrict__ Hin, const u16* __restrict__ Wp,
                 const float* __restrict__ dinv, void* __restrict__ Gout, int n) {
    constexpr int NT = DOUT / 16;
    int tid = threadIdx.x;
    int w = tid >> 6, l = tid & 63;
    int r0 = blockIdx.x * 128 + w * 32;
    int arow0 = r0 + (l & 15);
    int arow1 = arow0 + 16;
    bool av0 = arow0 < n, av1 = arow1 < n;
    const s16x8* A0 = (const s16x8*)((const u16*)Hin + (size_t)arow0 * 128);
    const s16x8* A1 = (const s16x8*)((const u16*)Hin + (size_t)arow1 * 128);
    const float* A032 = (const float*)Hin + (size_t)arow0 * 128;
    const float* A132 = (const float*)Hin + (size_t)arow1 * 128;
    const s16x8* Wp8 = (const s16x8*)Wp;
    const s16x8 zero = {0, 0, 0, 0, 0, 0, 0, 0};

    f32x4 acc0[NT], acc1[NT];
#pragma unroll
    for (int t = 0; t < NT; t++) { acc0[t] = {0.f,0.f,0.f,0.f}; acc1[t] = {0.f,0.f,0.f,0.f}; }

#pragma unroll
    for (int kk = 0; kk < 4; kk++) {                 // K = 128 = 4 x 32
        s16x8 a0, a1;
        if (AF32) {
            a0 = zero; a1 = zero;
            if (av0) {
                const f32x4* p = (const f32x4*)(A032 + kk * 32 + ((l >> 4) << 3));
                f32x4 f0 = p[0], f1 = p[1];
                a0[0]=(short)f2bf(f0[0]); a0[1]=(short)f2bf(f0[1]);
                a0[2]=(short)f2bf(f0[2]); a0[3]=(short)f2bf(f0[3]);
                a0[4]=(short)f2bf(f1[0]); a0[5]=(short)f2bf(f1[1]);
                a0[6]=(short)f2bf(f1[2]); a0[7]=(short)f2bf(f1[3]);
            }
            if (av1) {
                const f32x4* p = (const f32x4*)(A132 + kk * 32 + ((l >> 4) << 3));
                f32x4 f0 = p[0], f1 = p[1];
                a1[0]=(short)f2bf(f0[0]); a1[1]=(short)f2bf(f0[1]);
                a1[2]=(short)f2bf(f0[2]); a1[3]=(short)f2bf(f0[3]);
                a1[4]=(short)f2bf(f1[0]); a1[5]=(short)f2bf(f1[1]);
                a1[6]=(short)f2bf(f1[2]); a1[7]=(short)f2bf(f1[3]);
            }
        } else {
            a0 = av0 ? A0[kk * 4 + (l >> 4)] : zero;
            a1 = av1 ? A1[kk * 4 + (l >> 4)] : zero;
        }
#pragma unroll
        for (int t = 0; t < NT; t++) {
            s16x8 b = Wp8[(t * 4 + kk) * 64 + l];
            acc0[t] = __builtin_amdgcn_mfma_f32_16x16x32_bf16(a0, b, acc0[t], 0, 0, 0);
            acc1[t] = __builtin_amdgcn_mfma_f32_16x16x32_bf16(a1, b, acc1[t], 0, 0, 0);
        }
    }

    int col = l & 15;
#pragma unroll
    for (int r = 0; r < 4; r++) {
        int gr0 = r0 + (l >> 4) * 4 + r;
        if (gr0 < n) {
            float di = dinv[gr0];
#pragma unroll
            for (int t = 0; t < NT; t++) {
                float v = acc0[t][r] * di;
                if (OB16) ((u16*)Gout)[(size_t)gr0 * DOUT + t * 16 + col] = f2bf(v);
                else      ((float*)Gout)[(size_t)gr0 * DOUT + t * 16 + col] = v;
            }
        }
        int gr1 = gr0 + 16;
        if (gr1 < n) {
            float di = dinv[gr1];
#pragma unroll
            for (int t = 0; t < NT; t++) {
                float v = acc1[t][r] * di;
                if (OB16) ((u16*)Gout)[(size_t)gr1 * DOUT + t * 16 + col] = f2bf(v);
                else      ((float*)Gout)[(size_t)gr1 * DOUT + t * 16 + col] = v;
            }
        }
    }
}

// ---------------- aggregation (gather) ----------------
// 4 nodes per wave (16-lane groups), degree-sorted via order[] so the 4 nodes
// share ~the same degree (no max-of-4 divergence tail). 16B/lane uint4 gathers,
// unroll-by-4 independent chains; fp32 accumulate; bf16 out.

#define ACC8(A, U) \
    A[0] += bflo(U.x); A[1] += bfhi(U.x); A[2] += bflo(U.y); A[3] += bfhi(U.y); \
    A[4] += bflo(U.z); A[5] += bfhi(U.z); A[6] += bflo(U.w); A[7] += bfhi(U.w);

__global__ __launch_bounds__(256)
void k_agg_relu(const uint4* __restrict__ G, const int* __restrict__ offs,
                const int* __restrict__ deg, const int* __restrict__ srcs,
                const int* __restrict__ order,
                const float* __restrict__ dinv, const float* __restrict__ bias,
                uint4* __restrict__ out, int n) {
    int t = blockIdx.x * 256 + threadIdx.x;
    int wv = t >> 6;
    int lane = t & 63;
    int hl = lane & 15;                 // lane within 16-lane group
    int gnode = wv * 4 + (lane >> 4);   // 4 nodes per wave
    if (gnode >= n) return;
    int node = order[gnode];

    uint4 us = G[(size_t)node * 16 + hl];          // self-loop
    float a0[8], a1[8], a2[8], a3[8];
    a0[0] = bflo(us.x); a0[1] = bfhi(us.x); a0[2] = bflo(us.y); a0[3] = bfhi(us.y);
    a0[4] = bflo(us.z); a0[5] = bfhi(us.z); a0[6] = bflo(us.w); a0[7] = bfhi(us.w);
#pragma unroll
    for (int i = 0; i < 8; i++) { a1[i] = 0.f; a2[i] = 0.f; a3[i] = 0.f; }

    int start = offs[node];
    int cnt = deg[node];
    int j = 0;
    for (; j + 4 <= cnt; j += 4) {
        int s0 = srcs[start + j + 0];
        int s1 = srcs[start + j + 1];
        int s2 = srcs[start + j + 2];
        int s3 = srcs[start + j + 3];
        uint4 u0 = G[(size_t)s0 * 16 + hl];
        uint4 u1 = G[(size_t)s1 * 16 + hl];
        uint4 u2 = G[(size_t)s2 * 16 + hl];
        uint4 u3 = G[(size_t)s3 * 16 + hl];
        ACC8(a0, u0) ACC8(a1, u1) ACC8(a2, u2) ACC8(a3, u3)
    }
    for (; j < cnt; j++) {
        int s = srcs[start + j];
        uint4 u = G[(size_t)s * 16 + hl];
        ACC8(a0, u)
    }

    float di = dinv[node];
    const float4* b8 = (const float4*)bias;
    float4 b0 = b8[hl * 2], b1 = b8[hl * 2 + 1];
    float bb[8] = {b0.x, b0.y, b0.z, b0.w, b1.x, b1.y, b1.z, b1.w};
    float r[8];
#pragma unroll
    for (int i = 0; i < 8; i++) {
        float s = (a0[i] + a1[i]) + (a2[i] + a3[i]);
        r[i] = fmaxf(fmaf(s, di, bb[i]), 0.f);
    }
    out[(size_t)node * 16 + hl] =
        make_uint4(pk(r[0], r[1]), pk(r[2], r[3]), pk(r[4], r[5]), pk(r[6], r[7]));
}

#define ACC4(A, U) \
    A[0] += bflo(U.x); A[1] += bfhi(U.x); A[2] += bflo(U.y); A[3] += bfhi(U.y);

// final layer: G bf16 [n][64] = [n][16] uint2; 4 nodes/wave (degree-sorted),
// 4 features/lane. log_softmax: 4-wide local + 4 shfl_xor in 16-lane group.
__global__ __launch_bounds__(256)
void k_agg_softmax(const uint2* __restrict__ G, const int* __restrict__ offs,
                   const int* __restrict__ deg, const int* __restrict__ srcs,
                   const int* __restrict__ order,
                   const float* __restrict__ dinv, const float* __restrict__ bias,
                   float4* __restrict__ out, int n) {
    int t = blockIdx.x * 256 + threadIdx.x;
    int wv = t >> 6;
    int lane = t & 63;
    int hl = lane & 15;
    int gnode = wv * 4 + (lane >> 4);
    if (gnode >= n) return;
    int node = order[gnode];

    uint2 us = G[(size_t)node * 16 + hl];          // self-loop
    float a0[4], a1[4], a2[4], a3[4];
    a0[0] = bflo(us.x); a0[1] = bfhi(us.x); a0[2] = bflo(us.y); a0[3] = bfhi(us.y);
#pragma unroll
    for (int i = 0; i < 4; i++) { a1[i] = 0.f; a2[i] = 0.f; a3[i] = 0.f; }

    int start = offs[node];
    int cnt = deg[node];
    int j = 0;
    for (; j + 4 <= cnt; j += 4) {
        int s0 = srcs[start + j + 0];
        int s1 = srcs[start + j + 1];
        int s2 = srcs[start + j + 2];
        int s3 = srcs[start + j + 3];
        uint2 u0 = G[(size_t)s0 * 16 + hl];
        uint2 u1 = G[(size_t)s1 * 16 + hl];
        uint2 u2 = G[(size_t)s2 * 16 + hl];
        uint2 u3 = G[(size_t)s3 * 16 + hl];
        ACC4(a0, u0) ACC4(a1, u1) ACC4(a2, u2) ACC4(a3, u3)
    }
    for (; j < cnt; j++) {
        int s = srcs[start + j];
        uint2 u = G[(size_t)s * 16 + hl];
        ACC4(a0, u)
    }

    float di = dinv[node];
    float4 bb = ((const float4*)bias)[hl];
    float t0 = fmaf((a0[0] + a1[0]) + (a2[0] + a3[0]), di, bb.x);
    float t1 = fmaf((a0[1] + a1[1]) + (a2[1] + a3[1]), di, bb.y);
    float t2 = fmaf((a0[2] + a1[2]) + (a2[2] + a3[2]), di, bb.z);
    float t3 = fmaf((a0[3] + a1[3]) + (a2[3] + a3[3]), di, bb.w);
    float m = fmaxf(fmaxf(t0, t1), fmaxf(t2, t3));
#pragma unroll
    for (int off = 1; off < 16; off <<= 1) m = fmaxf(m, __shfl_xor(m, off, 64));
    float e = expf(t0 - m) + expf(t1 - m) + expf(t2 - m) + expf(t3 - m);
#pragma unroll
    for (int off = 1; off < 16; off <<= 1) e += __shfl_xor(e, off, 64);
    float lse = m + logf(e);
    out[(size_t)node * 16 + hl] = make_float4(t0 - lse, t1 - lse, t2 - lse, t3 - lse);
}

// ---------------- launch ----------------

extern "C" void kernel_launch(void* const* d_in, const int* in_sizes, int n_in,
                              void* d_out, int out_size, void* d_ws, size_t ws_size,
                              hipStream_t stream) {
    const float* x  = (const float*)d_in[0];
    const int*   ei = (const int*)d_in[1];
    const int*   row = ei;             // edge_index[0]: source
    const int*   col = ei + NE;        // edge_index[1]: destination
    const float* W1 = (const float*)d_in[2];
    const float* b1 = (const float*)d_in[3];
    const float* W2 = (const float*)d_in[4];
    const float* b2 = (const float*)d_in[5];
    const float* W3 = (const float*)d_in[6];
    const float* b3 = (const float*)d_in[7];
    float* outp = (float*)d_out;

    char* ws = (char*)d_ws;
    size_t off = 0;
    auto alloc = [&](size_t bytes) -> void* {
        void* p = (void*)(ws + off);
        off += (bytes + 255) & ~(size_t)255;
        return p;
    };
    float* dinv  = (float*)alloc((size_t)NN * 4);
    float* bufA  = (float*)alloc((size_t)NN * 128 * 4);   // bf16 G (all layers)
    u16*   bufB  = (u16*)alloc((size_t)NN * 128 * 2);     // bf16 H (layers 2,3)
    int*   deg   = (int*)alloc((size_t)NN * 4);
    int*   offs  = (int*)alloc((size_t)NN * 4);
    int*   cursor= (int*)alloc((size_t)NN * 4);
    int*   bsums = (int*)alloc(1024 * 4);
    int*   hist  = (int*)alloc(64 * 4);
    int*   bcur  = (int*)alloc(64 * 4);
    int*   order = (int*)alloc((size_t)NN * 4);
    int*   srcs  = (int*)alloc((size_t)NE * 4);
    u16*   wp1   = (u16*)alloc(128 * 128 * 2);
    u16*   wp2   = (u16*)alloc(128 * 128 * 2);
    u16*   wp3   = (u16*)alloc(128 * 64 * 2);

    int nbN = (NN + 255) / 256;   // 391
    int nbE = (NE + 255) / 256;

    k_init_deg <<<nbN, 256, 0, stream>>>(deg, hist, NN);
    k_deg_count<<<nbE, 256, 0, stream>>>(col, deg, NE);
    k_scan1    <<<nbN, 256, 0, stream>>>(deg, offs, bsums, dinv, hist, NN);
    k_scan2    <<<1,   512, 0, stream>>>(bsums, nbN);
    k_scan3    <<<nbN, 256, 0, stream>>>(offs, bsums, cursor, NN);
    k_fill     <<<nbE, 256, 0, stream>>>(row, col, cursor, srcs, NE);
    k_scan_bins<<<1,    64, 0, stream>>>(hist, bcur);
    k_scatter_nodes<<<nbN, 256, 0, stream>>>(deg, bcur, order, NN);
    k_pack_all <<<160, 256, 0, stream>>>(W1, W2, W3, wp1, wp2, wp3);

    int gb = (NN + 127) / 128;                  // 782 (128 rows/block)
    int ab4 = ((NN + 3) / 4 * 64 + 255) / 256;  // 4 nodes/wave -> 6250 blocks

    // layer 1: x(fp32, inline cvt) -> bufA(bf16 G) -> bufB(bf16 h1)
    k_gemm_mfma<128, true, true><<<gb, 256, 0, stream>>>(x, wp1, dinv, bufA, NN);
    k_agg_relu <<<ab4, 256, 0, stream>>>((uint4*)bufA, offs, deg, srcs, order, dinv, b1, (uint4*)bufB, NN);
    // layer 2: bufB -> bufA(bf16 G) -> bufB(bf16 h2)
    k_gemm_mfma<128, true, false><<<gb, 256, 0, stream>>>(bufB, wp2, dinv, bufA, NN);
    k_agg_relu <<<ab4, 256, 0, stream>>>((uint4*)bufA, offs, deg, srcs, order, dinv, b2, (uint4*)bufB, NN);
    // layer 3: bufB -> bufA(bf16 G, 64-wide) -> out (log_softmax)
    k_gemm_mfma<64, true, false><<<gb, 256, 0, stream>>>(bufB, wp3, dinv, bufA, NN);
    k_agg_softmax<<<ab4, 256, 0, stream>>>((uint2*)bufA, offs, deg, srcs, order, dinv, b3, (float4*)outp, NN);
}

// Round 13
// 310.754 us; speedup vs baseline: 3.3589x; 3.3589x over previous
//
#include <hip/hip_runtime.h>

#define NN 100000
#define NE 600000

typedef unsigned short u16;
typedef float f32x4 __attribute__((ext_vector_type(4)));
typedef short s16x8 __attribute__((ext_vector_type(8)));

__device__ inline u16 f2bf(float f) {            // fp32 -> bf16 RNE
    unsigned u = __float_as_uint(f);
    return (u16)((u + 0x7FFFu + ((u >> 16) & 1u)) >> 16);
}
__device__ inline float bflo(unsigned u) { return __uint_as_float(u << 16); }
__device__ inline float bfhi(unsigned u) { return __uint_as_float(u & 0xFFFF0000u); }
__device__ inline unsigned pk(float a, float b) {
    return (unsigned)f2bf(a) | ((unsigned)f2bf(b) << 16);
}

// ---------------- degree / CSR build ----------------

__global__ void k_init_deg(int* __restrict__ deg, int n) {
    int i = blockIdx.x * 256 + threadIdx.x;
    if (i < n) deg[i] = 0;
}

__global__ void k_deg_count(const int* __restrict__ col, int* __restrict__ deg, int E) {
    int e = blockIdx.x * 256 + threadIdx.x;
    if (e < E) atomicAdd(&deg[col[e]], 1);
}

// scan1: per-block exclusive scan of deg; dinv fused (no atomics!)
// NOTE round-12 lesson: NEVER fuse a 64-bin global atomic histogram here —
// 100k atomics on one cache line cross-XCD serialize to ~366 us.
__global__ void k_scan1(const int* __restrict__ deg, int* __restrict__ offs,
                        int* __restrict__ bsums, float* __restrict__ dinv, int n) {
    __shared__ int s[256];
    int t = threadIdx.x;
    int i = blockIdx.x * 256 + t;
    int v = (i < n) ? deg[i] : 0;
    if (i < n) dinv[i] = rsqrtf((float)(v + 1));   // +1: self-loop
    s[t] = v;
    __syncthreads();
    for (int off = 1; off < 256; off <<= 1) {
        int x = (t >= off) ? s[t - off] : 0;
        __syncthreads();
        s[t] += x;
        __syncthreads();
    }
    if (i < n) offs[i] = s[t] - v;
    if (t == 255) bsums[blockIdx.x] = s[255];
}

__global__ void k_scan2(int* __restrict__ bsums, int nb) {
    __shared__ int s[512];
    int t = threadIdx.x;
    int v = (t < nb) ? bsums[t] : 0;
    s[t] = v;
    __syncthreads();
    for (int off = 1; off < 512; off <<= 1) {
        int x = (t >= off) ? s[t - off] : 0;
        __syncthreads();
        s[t] += x;
        __syncthreads();
    }
    if (t < nb) bsums[t] = s[t] - v;
}

__global__ void k_scan3(int* __restrict__ offs, const int* __restrict__ bsums,
                        int* __restrict__ cursor, int n) {
    int i = blockIdx.x * 256 + threadIdx.x;
    if (i < n) {
        int o = offs[i] + bsums[i >> 8];
        offs[i] = o;
        cursor[i] = o;
    }
}

__global__ void k_fill(const int* __restrict__ row, const int* __restrict__ col,
                       int* __restrict__ cursor, int* __restrict__ srcs, int E) {
    int e = blockIdx.x * 256 + threadIdx.x;
    if (e < E) {
        int p = atomicAdd(&cursor[col[e]], 1);
        srcs[p] = row[e];
    }
}

// ---------------- W pack (all 3 weights, one launch) -------------------------
// Wp element ((t*4+kk)*64 + l)*8 + i  <-  W[kk*32 + (l>>4)*8 + i][t*16 + (l&15)]

__device__ inline void pack_one(const float* W, u16* Wp, int g, int DOUT) {
    int i  = g & 7;
    int l  = (g >> 3) & 63;
    int kk = (g >> 9) & 3;
    int t  = g >> 11;
    int k = kk * 32 + ((l >> 4) << 3) + i;
    int c = t * 16 + (l & 15);
    Wp[g] = f2bf(W[k * DOUT + c]);
}

__global__ __launch_bounds__(256)
void k_pack_all(const float* __restrict__ W1, const float* __restrict__ W2,
                const float* __restrict__ W3, u16* __restrict__ wp1,
                u16* __restrict__ wp2, u16* __restrict__ wp3) {
    int gid = blockIdx.x * 256 + threadIdx.x;
    if (gid < 16384) pack_one(W1, wp1, gid, 128);
    else if (gid < 32768) pack_one(W2, wp2, gid - 16384, 128);
    else if (gid < 40960) pack_one(W3, wp3, gid - 32768, 64);
}

// ---------------- GEMM: G = (H @ W) * dinv[row], bf16 MFMA, LDS-free ---------
// Block = 4 waves x 32 rows = 128 rows; each wave's 2 row-groups share B-frags.
// A-frag (16x16x32): lane l holds A[l&15][(l>>4)*8 + i].
// D: col=l&15, row=(l>>4)*4+reg  (guide §3, m89-verified).

template <int DOUT, bool OB16, bool AF32>
__global__ __launch_bounds__(256)
void k_gemm_mfma(const void* __restrict__ Hin, const u16* __restrict__ Wp,
                 const float* __restrict__ dinv, void* __restrict__ Gout, int n) {
    constexpr int NT = DOUT / 16;
    int tid = threadIdx.x;
    int w = tid >> 6, l = tid & 63;
    int r0 = blockIdx.x * 128 + w * 32;
    int arow0 = r0 + (l & 15);
    int arow1 = arow0 + 16;
    bool av0 = arow0 < n, av1 = arow1 < n;
    const s16x8* A0 = (const s16x8*)((const u16*)Hin + (size_t)arow0 * 128);
    const s16x8* A1 = (const s16x8*)((const u16*)Hin + (size_t)arow1 * 128);
    const float* A032 = (const float*)Hin + (size_t)arow0 * 128;
    const float* A132 = (const float*)Hin + (size_t)arow1 * 128;
    const s16x8* Wp8 = (const s16x8*)Wp;
    const s16x8 zero = {0, 0, 0, 0, 0, 0, 0, 0};

    f32x4 acc0[NT], acc1[NT];
#pragma unroll
    for (int t = 0; t < NT; t++) { acc0[t] = {0.f,0.f,0.f,0.f}; acc1[t] = {0.f,0.f,0.f,0.f}; }

#pragma unroll
    for (int kk = 0; kk < 4; kk++) {                 // K = 128 = 4 x 32
        s16x8 a0, a1;
        if (AF32) {
            a0 = zero; a1 = zero;
            if (av0) {
                const f32x4* p = (const f32x4*)(A032 + kk * 32 + ((l >> 4) << 3));
                f32x4 f0 = p[0], f1 = p[1];
                a0[0]=(short)f2bf(f0[0]); a0[1]=(short)f2bf(f0[1]);
                a0[2]=(short)f2bf(f0[2]); a0[3]=(short)f2bf(f0[3]);
                a0[4]=(short)f2bf(f1[0]); a0[5]=(short)f2bf(f1[1]);
                a0[6]=(short)f2bf(f1[2]); a0[7]=(short)f2bf(f1[3]);
            }
            if (av1) {
                const f32x4* p = (const f32x4*)(A132 + kk * 32 + ((l >> 4) << 3));
                f32x4 f0 = p[0], f1 = p[1];
                a1[0]=(short)f2bf(f0[0]); a1[1]=(short)f2bf(f0[1]);
                a1[2]=(short)f2bf(f0[2]); a1[3]=(short)f2bf(f0[3]);
                a1[4]=(short)f2bf(f1[0]); a1[5]=(short)f2bf(f1[1]);
                a1[6]=(short)f2bf(f1[2]); a1[7]=(short)f2bf(f1[3]);
            }
        } else {
            a0 = av0 ? A0[kk * 4 + (l >> 4)] : zero;
            a1 = av1 ? A1[kk * 4 + (l >> 4)] : zero;
        }
#pragma unroll
        for (int t = 0; t < NT; t++) {
            s16x8 b = Wp8[(t * 4 + kk) * 64 + l];
            acc0[t] = __builtin_amdgcn_mfma_f32_16x16x32_bf16(a0, b, acc0[t], 0, 0, 0);
            acc1[t] = __builtin_amdgcn_mfma_f32_16x16x32_bf16(a1, b, acc1[t], 0, 0, 0);
        }
    }

    int col = l & 15;
#pragma unroll
    for (int r = 0; r < 4; r++) {
        int gr0 = r0 + (l >> 4) * 4 + r;
        if (gr0 < n) {
            float di = dinv[gr0];
#pragma unroll
            for (int t = 0; t < NT; t++) {
                float v = acc0[t][r] * di;
                if (OB16) ((u16*)Gout)[(size_t)gr0 * DOUT + t * 16 + col] = f2bf(v);
                else      ((float*)Gout)[(size_t)gr0 * DOUT + t * 16 + col] = v;
            }
        }
        int gr1 = gr0 + 16;
        if (gr1 < n) {
            float di = dinv[gr1];
#pragma unroll
            for (int t = 0; t < NT; t++) {
                float v = acc1[t][r] * di;
                if (OB16) ((u16*)Gout)[(size_t)gr1 * DOUT + t * 16 + col] = f2bf(v);
                else      ((float*)Gout)[(size_t)gr1 * DOUT + t * 16 + col] = v;
            }
        }
    }
}

// ---------------- aggregation (gather) ----------------
// 4 nodes per wave (16-lane groups), 16B/lane uint4 gathers, unroll-by-4
// independent chains; fp32 accumulate; bf16 out. Natural node order
// (round-12 lesson: degree-sort costs more than its divergence gain).

#define ACC8(A, U) \
    A[0] += bflo(U.x); A[1] += bfhi(U.x); A[2] += bflo(U.y); A[3] += bfhi(U.y); \
    A[4] += bflo(U.z); A[5] += bfhi(U.z); A[6] += bflo(U.w); A[7] += bfhi(U.w);

__global__ __launch_bounds__(256)
void k_agg_relu(const uint4* __restrict__ G, const int* __restrict__ offs,
                const int* __restrict__ deg, const int* __restrict__ srcs,
                const float* __restrict__ dinv, const float* __restrict__ bias,
                uint4* __restrict__ out, int n) {
    int t = blockIdx.x * 256 + threadIdx.x;
    int wv = t >> 6;
    int lane = t & 63;
    int hl = lane & 15;                 // lane within 16-lane group
    int node = wv * 4 + (lane >> 4);    // 4 nodes per wave
    if (node >= n) return;

    uint4 us = G[(size_t)node * 16 + hl];          // self-loop
    float a0[8], a1[8], a2[8], a3[8];
    a0[0] = bflo(us.x); a0[1] = bfhi(us.x); a0[2] = bflo(us.y); a0[3] = bfhi(us.y);
    a0[4] = bflo(us.z); a0[5] = bfhi(us.z); a0[6] = bflo(us.w); a0[7] = bfhi(us.w);
#pragma unroll
    for (int i = 0; i < 8; i++) { a1[i] = 0.f; a2[i] = 0.f; a3[i] = 0.f; }

    int start = offs[node];
    int cnt = deg[node];
    int j = 0;
    for (; j + 4 <= cnt; j += 4) {
        int s0 = srcs[start + j + 0];
        int s1 = srcs[start + j + 1];
        int s2 = srcs[start + j + 2];
        int s3 = srcs[start + j + 3];
        uint4 u0 = G[(size_t)s0 * 16 + hl];
        uint4 u1 = G[(size_t)s1 * 16 + hl];
        uint4 u2 = G[(size_t)s2 * 16 + hl];
        uint4 u3 = G[(size_t)s3 * 16 + hl];
        ACC8(a0, u0) ACC8(a1, u1) ACC8(a2, u2) ACC8(a3, u3)
    }
    for (; j < cnt; j++) {
        int s = srcs[start + j];
        uint4 u = G[(size_t)s * 16 + hl];
        ACC8(a0, u)
    }

    float di = dinv[node];
    const float4* b8 = (const float4*)bias;
    float4 b0 = b8[hl * 2], b1 = b8[hl * 2 + 1];
    float bb[8] = {b0.x, b0.y, b0.z, b0.w, b1.x, b1.y, b1.z, b1.w};
    float r[8];
#pragma unroll
    for (int i = 0; i < 8; i++) {
        float s = (a0[i] + a1[i]) + (a2[i] + a3[i]);
        r[i] = fmaxf(fmaf(s, di, bb[i]), 0.f);
    }
    out[(size_t)node * 16 + hl] =
        make_uint4(pk(r[0], r[1]), pk(r[2], r[3]), pk(r[4], r[5]), pk(r[6], r[7]));
}

#define ACC4(A, U) \
    A[0] += bflo(U.x); A[1] += bfhi(U.x); A[2] += bflo(U.y); A[3] += bfhi(U.y);

// final layer: G bf16 [n][64] = [n][16] uint2; 4 nodes/wave, 4 features/lane.
// log_softmax: 4-wide local + 4 shfl_xor within the 16-lane group; float4 out.
__global__ __launch_bounds__(256)
void k_agg_softmax(const uint2* __restrict__ G, const int* __restrict__ offs,
                   const int* __restrict__ deg, const int* __restrict__ srcs,
                   const float* __restrict__ dinv, const float* __restrict__ bias,
                   float4* __restrict__ out, int n) {
    int t = blockIdx.x * 256 + threadIdx.x;
    int wv = t >> 6;
    int lane = t & 63;
    int hl = lane & 15;
    int node = wv * 4 + (lane >> 4);
    if (node >= n) return;

    uint2 us = G[(size_t)node * 16 + hl];          // self-loop
    float a0[4], a1[4], a2[4], a3[4];
    a0[0] = bflo(us.x); a0[1] = bfhi(us.x); a0[2] = bflo(us.y); a0[3] = bfhi(us.y);
#pragma unroll
    for (int i = 0; i < 4; i++) { a1[i] = 0.f; a2[i] = 0.f; a3[i] = 0.f; }

    int start = offs[node];
    int cnt = deg[node];
    int j = 0;
    for (; j + 4 <= cnt; j += 4) {
        int s0 = srcs[start + j + 0];
        int s1 = srcs[start + j + 1];
        int s2 = srcs[start + j + 2];
        int s3 = srcs[start + j + 3];
        uint2 u0 = G[(size_t)s0 * 16 + hl];
        uint2 u1 = G[(size_t)s1 * 16 + hl];
        uint2 u2 = G[(size_t)s2 * 16 + hl];
        uint2 u3 = G[(size_t)s3 * 16 + hl];
        ACC4(a0, u0) ACC4(a1, u1) ACC4(a2, u2) ACC4(a3, u3)
    }
    for (; j < cnt; j++) {
        int s = srcs[start + j];
        uint2 u = G[(size_t)s * 16 + hl];
        ACC4(a0, u)
    }

    float di = dinv[node];
    float4 bb = ((const float4*)bias)[hl];
    float t0 = fmaf((a0[0] + a1[0]) + (a2[0] + a3[0]), di, bb.x);
    float t1 = fmaf((a0[1] + a1[1]) + (a2[1] + a3[1]), di, bb.y);
    float t2 = fmaf((a0[2] + a1[2]) + (a2[2] + a3[2]), di, bb.z);
    float t3 = fmaf((a0[3] + a1[3]) + (a2[3] + a3[3]), di, bb.w);
    float m = fmaxf(fmaxf(t0, t1), fmaxf(t2, t3));
#pragma unroll
    for (int off = 1; off < 16; off <<= 1) m = fmaxf(m, __shfl_xor(m, off, 64));
    float e = expf(t0 - m) + expf(t1 - m) + expf(t2 - m) + expf(t3 - m);
#pragma unroll
    for (int off = 1; off < 16; off <<= 1) e += __shfl_xor(e, off, 64);
    float lse = m + logf(e);
    out[(size_t)node * 16 + hl] = make_float4(t0 - lse, t1 - lse, t2 - lse, t3 - lse);
}

// ---------------- launch ----------------

extern "C" void kernel_launch(void* const* d_in, const int* in_sizes, int n_in,
                              void* d_out, int out_size, void* d_ws, size_t ws_size,
                              hipStream_t stream) {
    const float* x  = (const float*)d_in[0];
    const int*   ei = (const int*)d_in[1];
    const int*   row = ei;             // edge_index[0]: source
    const int*   col = ei + NE;        // edge_index[1]: destination
    const float* W1 = (const float*)d_in[2];
    const float* b1 = (const float*)d_in[3];
    const float* W2 = (const float*)d_in[4];
    const float* b2 = (const float*)d_in[5];
    const float* W3 = (const float*)d_in[6];
    const float* b3 = (const float*)d_in[7];
    float* outp = (float*)d_out;

    char* ws = (char*)d_ws;
    size_t off = 0;
    auto alloc = [&](size_t bytes) -> void* {
        void* p = (void*)(ws + off);
        off += (bytes + 255) & ~(size_t)255;
        return p;
    };
    float* dinv  = (float*)alloc((size_t)NN * 4);
    float* bufA  = (float*)alloc((size_t)NN * 128 * 4);   // bf16 G (all layers)
    u16*   bufB  = (u16*)alloc((size_t)NN * 128 * 2);     // bf16 H (layers 2,3)
    int*   deg   = (int*)alloc((size_t)NN * 4);
    int*   offs  = (int*)alloc((size_t)NN * 4);
    int*   cursor= (int*)alloc((size_t)NN * 4);
    int*   bsums = (int*)alloc(1024 * 4);
    int*   srcs  = (int*)alloc((size_t)NE * 4);
    u16*   wp1   = (u16*)alloc(128 * 128 * 2);
    u16*   wp2   = (u16*)alloc(128 * 128 * 2);
    u16*   wp3   = (u16*)alloc(128 * 64 * 2);

    int nbN = (NN + 255) / 256;   // 391
    int nbE = (NE + 255) / 256;

    k_init_deg <<<nbN, 256, 0, stream>>>(deg, NN);
    k_deg_count<<<nbE, 256, 0, stream>>>(col, deg, NE);
    k_scan1    <<<nbN, 256, 0, stream>>>(deg, offs, bsums, dinv, NN);
    k_scan2    <<<1,   512, 0, stream>>>(bsums, nbN);
    k_scan3    <<<nbN, 256, 0, stream>>>(offs, bsums, cursor, NN);
    k_fill     <<<nbE, 256, 0, stream>>>(row, col, cursor, srcs, NE);
    k_pack_all <<<160, 256, 0, stream>>>(W1, W2, W3, wp1, wp2, wp3);

    int gb = (NN + 127) / 128;                  // 782 (128 rows/block)
    int ab4 = ((NN + 3) / 4 * 64 + 255) / 256;  // 4 nodes/wave -> 6250 blocks

    // layer 1: x(fp32, inline cvt) -> bufA(bf16 G) -> bufB(bf16 h1)
    k_gemm_mfma<128, true, true><<<gb, 256, 0, stream>>>(x, wp1, dinv, bufA, NN);
    k_agg_relu <<<ab4, 256, 0, stream>>>((uint4*)bufA, offs, deg, srcs, dinv, b1, (uint4*)bufB, NN);
    // layer 2: bufB -> bufA(bf16 G) -> bufB(bf16 h2)
    k_gemm_mfma<128, true, false><<<gb, 256, 0, stream>>>(bufB, wp2, dinv, bufA, NN);
    k_agg_relu <<<ab4, 256, 0, stream>>>((uint4*)bufA, offs, deg, srcs, dinv, b2, (uint4*)bufB, NN);
    // layer 3: bufB -> bufA(bf16 G, 64-wide) -> out (log_softmax)
    k_gemm_mfma<64, true, false><<<gb, 256, 0, stream>>>(bufB, wp3, dinv, bufA, NN);
    k_agg_softmax<<<ab4, 256, 0, stream>>>((uint2*)bufA, offs, deg, srcs, dinv, b3, (float4*)outp, NN);
}

// Round 14
// 302.448 us; speedup vs baseline: 3.4512x; 1.0275x over previous
//
#include <hip/hip_runtime.h>

#define NN 100000
#define NE 600000

typedef unsigned short u16;
typedef float f32x4 __attribute__((ext_vector_type(4)));
typedef short s16x8 __attribute__((ext_vector_type(8)));

__device__ inline u16 f2bf(float f) {            // fp32 -> bf16 RNE
    unsigned u = __float_as_uint(f);
    return (u16)((u + 0x7FFFu + ((u >> 16) & 1u)) >> 16);
}
__device__ inline float bflo(unsigned u) { return __uint_as_float(u << 16); }
__device__ inline float bfhi(unsigned u) { return __uint_as_float(u & 0xFFFF0000u); }
__device__ inline unsigned pk(float a, float b) {
    return (unsigned)f2bf(a) | ((unsigned)f2bf(b) << 16);
}

// ---------------- degree / CSR build ----------------

__global__ void k_init_deg(int* __restrict__ deg, int n) {
    int i = blockIdx.x * 256 + threadIdx.x;
    if (i < n) deg[i] = 0;
}

__global__ void k_deg_count(const int* __restrict__ col, int* __restrict__ deg, int E) {
    int e = blockIdx.x * 256 + threadIdx.x;
    if (e < E) atomicAdd(&deg[col[e]], 1);
}

// scan1: per-block exclusive scan of deg; dinv fused (no atomics!)
// round-12 lesson: NEVER fuse a small-bin global atomic histogram here.
__global__ void k_scan1(const int* __restrict__ deg, int* __restrict__ offs,
                        int* __restrict__ bsums, float* __restrict__ dinv, int n) {
    __shared__ int s[256];
    int t = threadIdx.x;
    int i = blockIdx.x * 256 + t;
    int v = (i < n) ? deg[i] : 0;
    if (i < n) dinv[i] = rsqrtf((float)(v + 1));   // +1: self-loop
    s[t] = v;
    __syncthreads();
    for (int off = 1; off < 256; off <<= 1) {
        int x = (t >= off) ? s[t - off] : 0;
        __syncthreads();
        s[t] += x;
        __syncthreads();
    }
    if (i < n) offs[i] = s[t] - v;
    if (t == 255) bsums[blockIdx.x] = s[255];
}

__global__ void k_scan2(int* __restrict__ bsums, int nb) {
    __shared__ int s[512];
    int t = threadIdx.x;
    int v = (t < nb) ? bsums[t] : 0;
    s[t] = v;
    __syncthreads();
    for (int off = 1; off < 512; off <<= 1) {
        int x = (t >= off) ? s[t - off] : 0;
        __syncthreads();
        s[t] += x;
        __syncthreads();
    }
    if (t < nb) bsums[t] = s[t] - v;
}

__global__ void k_scan3(int* __restrict__ offs, const int* __restrict__ bsums,
                        int* __restrict__ cursor, int n) {
    int i = blockIdx.x * 256 + threadIdx.x;
    if (i < n) {
        int o = offs[i] + bsums[i >> 8];
        offs[i] = o;
        cursor[i] = o;
    }
}

__global__ void k_fill(const int* __restrict__ row, const int* __restrict__ col,
                       int* __restrict__ cursor, int* __restrict__ srcs, int E) {
    int e = blockIdx.x * 256 + threadIdx.x;
    if (e < E) {
        int p = atomicAdd(&cursor[col[e]], 1);
        srcs[p] = row[e];
    }
}

// ---------------- W pack (all 3 weights, one launch) + bufA zero-row ---------
// Wp element ((t*4+kk)*64 + l)*8 + i  <-  W[kk*32 + (l>>4)*8 + i][t*16 + (l&15)]
// Also zeroes bufA bytes [NN*256, NN*256+256): the "zero row" used by the aggs'
// predicated batch-8 gathers (index NN in 256B-row layout, 2*NN in 128B layout).
// No GEMM writes rows >= NN, so it stays zero through all three layers.

__device__ inline void pack_one(const float* W, u16* Wp, int g, int DOUT) {
    int i  = g & 7;
    int l  = (g >> 3) & 63;
    int kk = (g >> 9) & 3;
    int t  = g >> 11;
    int k = kk * 32 + ((l >> 4) << 3) + i;
    int c = t * 16 + (l & 15);
    Wp[g] = f2bf(W[k * DOUT + c]);
}

__global__ __launch_bounds__(256)
void k_pack_all(const float* __restrict__ W1, const float* __restrict__ W2,
                const float* __restrict__ W3, u16* __restrict__ wp1,
                u16* __restrict__ wp2, u16* __restrict__ wp3,
                uint4* __restrict__ bufA) {
    int gid = blockIdx.x * 256 + threadIdx.x;
    if (gid < 16384) pack_one(W1, wp1, gid, 128);
    else if (gid < 32768) pack_one(W2, wp2, gid - 16384, 128);
    else if (gid < 40960) pack_one(W3, wp3, gid - 32768, 64);
    else if (gid < 40976) bufA[(size_t)NN * 16 + (gid - 40960)] = make_uint4(0, 0, 0, 0);
}

// ---------------- GEMM: G = (H @ W) * dinv[row], bf16 MFMA, LDS-free ---------
// Block = 4 waves x 32 rows = 128 rows; each wave's 2 row-groups share B-frags.
// A-frag (16x16x32): lane l holds A[l&15][(l>>4)*8 + i].
// D: col=l&15, row=(l>>4)*4+reg  (guide §3, m89-verified).

template <int DOUT, bool OB16, bool AF32>
__global__ __launch_bounds__(256)
void k_gemm_mfma(const void* __restrict__ Hin, const u16* __restrict__ Wp,
                 const float* __restrict__ dinv, void* __restrict__ Gout, int n) {
    constexpr int NT = DOUT / 16;
    int tid = threadIdx.x;
    int w = tid >> 6, l = tid & 63;
    int r0 = blockIdx.x * 128 + w * 32;
    int arow0 = r0 + (l & 15);
    int arow1 = arow0 + 16;
    bool av0 = arow0 < n, av1 = arow1 < n;
    const s16x8* A0 = (const s16x8*)((const u16*)Hin + (size_t)arow0 * 128);
    const s16x8* A1 = (const s16x8*)((const u16*)Hin + (size_t)arow1 * 128);
    const float* A032 = (const float*)Hin + (size_t)arow0 * 128;
    const float* A132 = (const float*)Hin + (size_t)arow1 * 128;
    const s16x8* Wp8 = (const s16x8*)Wp;
    const s16x8 zero = {0, 0, 0, 0, 0, 0, 0, 0};

    f32x4 acc0[NT], acc1[NT];
#pragma unroll
    for (int t = 0; t < NT; t++) { acc0[t] = {0.f,0.f,0.f,0.f}; acc1[t] = {0.f,0.f,0.f,0.f}; }

#pragma unroll
    for (int kk = 0; kk < 4; kk++) {                 // K = 128 = 4 x 32
        s16x8 a0, a1;
        if (AF32) {
            a0 = zero; a1 = zero;
            if (av0) {
                const f32x4* p = (const f32x4*)(A032 + kk * 32 + ((l >> 4) << 3));
                f32x4 f0 = p[0], f1 = p[1];
                a0[0]=(short)f2bf(f0[0]); a0[1]=(short)f2bf(f0[1]);
                a0[2]=(short)f2bf(f0[2]); a0[3]=(short)f2bf(f0[3]);
                a0[4]=(short)f2bf(f1[0]); a0[5]=(short)f2bf(f1[1]);
                a0[6]=(short)f2bf(f1[2]); a0[7]=(short)f2bf(f1[3]);
            }
            if (av1) {
                const f32x4* p = (const f32x4*)(A132 + kk * 32 + ((l >> 4) << 3));
                f32x4 f0 = p[0], f1 = p[1];
                a1[0]=(short)f2bf(f0[0]); a1[1]=(short)f2bf(f0[1]);
                a1[2]=(short)f2bf(f0[2]); a1[3]=(short)f2bf(f0[3]);
                a1[4]=(short)f2bf(f1[0]); a1[5]=(short)f2bf(f1[1]);
                a1[6]=(short)f2bf(f1[2]); a1[7]=(short)f2bf(f1[3]);
            }
        } else {
            a0 = av0 ? A0[kk * 4 + (l >> 4)] : zero;
            a1 = av1 ? A1[kk * 4 + (l >> 4)] : zero;
        }
#pragma unroll
        for (int t = 0; t < NT; t++) {
            s16x8 b = Wp8[(t * 4 + kk) * 64 + l];
            acc0[t] = __builtin_amdgcn_mfma_f32_16x16x32_bf16(a0, b, acc0[t], 0, 0, 0);
            acc1[t] = __builtin_amdgcn_mfma_f32_16x16x32_bf16(a1, b, acc1[t], 0, 0, 0);
        }
    }

    int col = l & 15;
#pragma unroll
    for (int r = 0; r < 4; r++) {
        int gr0 = r0 + (l >> 4) * 4 + r;
        if (gr0 < n) {
            float di = dinv[gr0];
#pragma unroll
            for (int t = 0; t < NT; t++) {
                float v = acc0[t][r] * di;
                if (OB16) ((u16*)Gout)[(size_t)gr0 * DOUT + t * 16 + col] = f2bf(v);
                else      ((float*)Gout)[(size_t)gr0 * DOUT + t * 16 + col] = v;
            }
        }
        int gr1 = gr0 + 16;
        if (gr1 < n) {
            float di = dinv[gr1];
#pragma unroll
            for (int t = 0; t < NT; t++) {
                float v = acc1[t][r] * di;
                if (OB16) ((u16*)Gout)[(size_t)gr1 * DOUT + t * 16 + col] = f2bf(v);
                else      ((float*)Gout)[(size_t)gr1 * DOUT + t * 16 + col] = v;
            }
        }
    }
}

// ---------------- aggregation (gather) ----------------
// 4 nodes per wave (16-lane groups). Predicated batch-8: every batch issues 8
// INDEPENDENT gathers (invalid slots -> the zeroed row, adds are exact no-ops),
// so a deg<=8 node pays ONE memory-latency exposure instead of a serial tail.
// srcs is padded by 8 ints so index loads never fault; selected away if invalid.

#define ACC8(A, U) \
    A[0] += bflo(U.x); A[1] += bfhi(U.x); A[2] += bflo(U.y); A[3] += bfhi(U.y); \
    A[4] += bflo(U.z); A[5] += bfhi(U.z); A[6] += bflo(U.w); A[7] += bfhi(U.w);

__global__ __launch_bounds__(256)
void k_agg_relu(const uint4* __restrict__ G, const int* __restrict__ offs,
                const int* __restrict__ deg, const int* __restrict__ srcs,
                const float* __restrict__ dinv, const float* __restrict__ bias,
                uint4* __restrict__ out, int n) {
    int t = blockIdx.x * 256 + threadIdx.x;
    int wv = t >> 6;
    int lane = t & 63;
    int hl = lane & 15;                 // lane within 16-lane group
    int node = wv * 4 + (lane >> 4);    // 4 nodes per wave
    if (node >= n) return;
    const int ZR = NN;                  // zero row (256B layout)

    uint4 us = G[(size_t)node * 16 + hl];          // self-loop
    float a0[8], a1[8], a2[8], a3[8];
    a0[0] = bflo(us.x); a0[1] = bfhi(us.x); a0[2] = bflo(us.y); a0[3] = bfhi(us.y);
    a0[4] = bflo(us.z); a0[5] = bfhi(us.z); a0[6] = bflo(us.w); a0[7] = bfhi(us.w);
#pragma unroll
    for (int i = 0; i < 8; i++) { a1[i] = 0.f; a2[i] = 0.f; a3[i] = 0.f; }

    int start = offs[node];
    int cnt = deg[node];
    int nb = (cnt + 7) >> 3;
    for (int b = 0; b < nb; b++) {
        int j = b * 8, base = start + j;
        int t0 = srcs[base + 0], t1 = srcs[base + 1];
        int t2 = srcs[base + 2], t3 = srcs[base + 3];
        int t4 = srcs[base + 4], t5 = srcs[base + 5];
        int t6 = srcs[base + 6], t7 = srcs[base + 7];
        int s0 = t0;                            // j < cnt guaranteed
        int s1 = (j + 1 < cnt) ? t1 : ZR;
        int s2 = (j + 2 < cnt) ? t2 : ZR;
        int s3 = (j + 3 < cnt) ? t3 : ZR;
        int s4 = (j + 4 < cnt) ? t4 : ZR;
        int s5 = (j + 5 < cnt) ? t5 : ZR;
        int s6 = (j + 6 < cnt) ? t6 : ZR;
        int s7 = (j + 7 < cnt) ? t7 : ZR;
        uint4 u0 = G[(size_t)s0 * 16 + hl];
        uint4 u1 = G[(size_t)s1 * 16 + hl];
        uint4 u2 = G[(size_t)s2 * 16 + hl];
        uint4 u3 = G[(size_t)s3 * 16 + hl];
        uint4 u4 = G[(size_t)s4 * 16 + hl];
        uint4 u5 = G[(size_t)s5 * 16 + hl];
        uint4 u6 = G[(size_t)s6 * 16 + hl];
        uint4 u7 = G[(size_t)s7 * 16 + hl];
        ACC8(a0, u0) ACC8(a1, u1) ACC8(a2, u2) ACC8(a3, u3)
        ACC8(a0, u4) ACC8(a1, u5) ACC8(a2, u6) ACC8(a3, u7)
    }

    float di = dinv[node];
    const float4* b8 = (const float4*)bias;
    float4 b0 = b8[hl * 2], b1 = b8[hl * 2 + 1];
    float bb[8] = {b0.x, b0.y, b0.z, b0.w, b1.x, b1.y, b1.z, b1.w};
    float r[8];
#pragma unroll
    for (int i = 0; i < 8; i++) {
        float s = (a0[i] + a1[i]) + (a2[i] + a3[i]);
        r[i] = fmaxf(fmaf(s, di, bb[i]), 0.f);
    }
    out[(size_t)node * 16 + hl] =
        make_uint4(pk(r[0], r[1]), pk(r[2], r[3]), pk(r[4], r[5]), pk(r[6], r[7]));
}

#define ACC4(A, U) \
    A[0] += bflo(U.x); A[1] += bfhi(U.x); A[2] += bflo(U.y); A[3] += bfhi(U.y);

// final layer: G bf16 [n][64] = [n][16] uint2; 4 nodes/wave, 4 features/lane.
// Predicated batch-8 gathers (zero row index 2*NN in the 128B-row layout).
__global__ __launch_bounds__(256)
void k_agg_softmax(const uint2* __restrict__ G, const int* __restrict__ offs,
                   const int* __restrict__ deg, const int* __restrict__ srcs,
                   const float* __restrict__ dinv, const float* __restrict__ bias,
                   float4* __restrict__ out, int n) {
    int t = blockIdx.x * 256 + threadIdx.x;
    int wv = t >> 6;
    int lane = t & 63;
    int hl = lane & 15;
    int node = wv * 4 + (lane >> 4);
    if (node >= n) return;
    const int ZR = 2 * NN;              // zero row (128B layout; same bytes as NN*256)

    uint2 us = G[(size_t)node * 16 + hl];          // self-loop
    float a0[4], a1[4], a2[4], a3[4];
    a0[0] = bflo(us.x); a0[1] = bfhi(us.x); a0[2] = bflo(us.y); a0[3] = bfhi(us.y);
#pragma unroll
    for (int i = 0; i < 4; i++) { a1[i] = 0.f; a2[i] = 0.f; a3[i] = 0.f; }

    int start = offs[node];
    int cnt = deg[node];
    int nb = (cnt + 7) >> 3;
    for (int b = 0; b < nb; b++) {
        int j = b * 8, base = start + j;
        int t0 = srcs[base + 0], t1 = srcs[base + 1];
        int t2 = srcs[base + 2], t3 = srcs[base + 3];
        int t4 = srcs[base + 4], t5 = srcs[base + 5];
        int t6 = srcs[base + 6], t7 = srcs[base + 7];
        int s0 = t0;
        int s1 = (j + 1 < cnt) ? t1 : ZR;
        int s2 = (j + 2 < cnt) ? t2 : ZR;
        int s3 = (j + 3 < cnt) ? t3 : ZR;
        int s4 = (j + 4 < cnt) ? t4 : ZR;
        int s5 = (j + 5 < cnt) ? t5 : ZR;
        int s6 = (j + 6 < cnt) ? t6 : ZR;
        int s7 = (j + 7 < cnt) ? t7 : ZR;
        uint2 u0 = G[(size_t)s0 * 16 + hl];
        uint2 u1 = G[(size_t)s1 * 16 + hl];
        uint2 u2 = G[(size_t)s2 * 16 + hl];
        uint2 u3 = G[(size_t)s3 * 16 + hl];
        uint2 u4 = G[(size_t)s4 * 16 + hl];
        uint2 u5 = G[(size_t)s5 * 16 + hl];
        uint2 u6 = G[(size_t)s6 * 16 + hl];
        uint2 u7 = G[(size_t)s7 * 16 + hl];
        ACC4(a0, u0) ACC4(a1, u1) ACC4(a2, u2) ACC4(a3, u3)
        ACC4(a0, u4) ACC4(a1, u5) ACC4(a2, u6) ACC4(a3, u7)
    }

    float di = dinv[node];
    float4 bb = ((const float4*)bias)[hl];
    float t0 = fmaf((a0[0] + a1[0]) + (a2[0] + a3[0]), di, bb.x);
    float t1 = fmaf((a0[1] + a1[1]) + (a2[1] + a3[1]), di, bb.y);
    float t2 = fmaf((a0[2] + a1[2]) + (a2[2] + a3[2]), di, bb.z);
    float t3 = fmaf((a0[3] + a1[3]) + (a2[3] + a3[3]), di, bb.w);
    float m = fmaxf(fmaxf(t0, t1), fmaxf(t2, t3));
#pragma unroll
    for (int off = 1; off < 16; off <<= 1) m = fmaxf(m, __shfl_xor(m, off, 64));
    float e = expf(t0 - m) + expf(t1 - m) + expf(t2 - m) + expf(t3 - m);
#pragma unroll
    for (int off = 1; off < 16; off <<= 1) e += __shfl_xor(e, off, 64);
    float lse = m + logf(e);
    out[(size_t)node * 16 + hl] = make_float4(t0 - lse, t1 - lse, t2 - lse, t3 - lse);
}

// ---------------- launch ----------------

extern "C" void kernel_launch(void* const* d_in, const int* in_sizes, int n_in,
                              void* d_out, int out_size, void* d_ws, size_t ws_size,
                              hipStream_t stream) {
    const float* x  = (const float*)d_in[0];
    const int*   ei = (const int*)d_in[1];
    const int*   row = ei;             // edge_index[0]: source
    const int*   col = ei + NE;        // edge_index[1]: destination
    const float* W1 = (const float*)d_in[2];
    const float* b1 = (const float*)d_in[3];
    const float* W2 = (const float*)d_in[4];
    const float* b2 = (const float*)d_in[5];
    const float* W3 = (const float*)d_in[6];
    const float* b3 = (const float*)d_in[7];
    float* outp = (float*)d_out;

    char* ws = (char*)d_ws;
    size_t off = 0;
    auto alloc = [&](size_t bytes) -> void* {
        void* p = (void*)(ws + off);
        off += (bytes + 255) & ~(size_t)255;
        return p;
    };
    float* dinv  = (float*)alloc((size_t)NN * 4);
    float* bufA  = (float*)alloc((size_t)NN * 128 * 4);   // bf16 G + zero row @ NN*256
    u16*   bufB  = (u16*)alloc((size_t)NN * 128 * 2);     // bf16 H (layers 2,3)
    int*   deg   = (int*)alloc((size_t)NN * 4);
    int*   offs  = (int*)alloc((size_t)NN * 4);
    int*   cursor= (int*)alloc((size_t)NN * 4);
    int*   bsums = (int*)alloc(1024 * 4);
    int*   srcs  = (int*)alloc(((size_t)NE + 8) * 4);     // +8 pad for batch-8 reads
    u16*   wp1   = (u16*)alloc(128 * 128 * 2);
    u16*   wp2   = (u16*)alloc(128 * 128 * 2);
    u16*   wp3   = (u16*)alloc(128 * 64 * 2);

    int nbN = (NN + 255) / 256;   // 391
    int nbE = (NE + 255) / 256;

    k_init_deg <<<nbN, 256, 0, stream>>>(deg, NN);
    k_deg_count<<<nbE, 256, 0, stream>>>(col, deg, NE);
    k_scan1    <<<nbN, 256, 0, stream>>>(deg, offs, bsums, dinv, NN);
    k_scan2    <<<1,   512, 0, stream>>>(bsums, nbN);
    k_scan3    <<<nbN, 256, 0, stream>>>(offs, bsums, cursor, NN);
    k_fill     <<<nbE, 256, 0, stream>>>(row, col, cursor, srcs, NE);
    k_pack_all <<<161, 256, 0, stream>>>(W1, W2, W3, wp1, wp2, wp3, (uint4*)bufA);

    int gb = (NN + 127) / 128;                  // 782 (128 rows/block)
    int ab4 = ((NN + 3) / 4 * 64 + 255) / 256;  // 4 nodes/wave -> 6250 blocks

    // layer 1: x(fp32, inline cvt) -> bufA(bf16 G) -> bufB(bf16 h1)
    k_gemm_mfma<128, true, true><<<gb, 256, 0, stream>>>(x, wp1, dinv, bufA, NN);
    k_agg_relu <<<ab4, 256, 0, stream>>>((uint4*)bufA, offs, deg, srcs, dinv, b1, (uint4*)bufB, NN);
    // layer 2: bufB -> bufA(bf16 G) -> bufB(bf16 h2)
    k_gemm_mfma<128, true, false><<<gb, 256, 0, stream>>>(bufB, wp2, dinv, bufA, NN);
    k_agg_relu <<<ab4, 256, 0, stream>>>((uint4*)bufA, offs, deg, srcs, dinv, b2, (uint4*)bufB, NN);
    // layer 3: bufB -> bufA(bf16 G, 64-wide) -> out (log_softmax)
    k_gemm_mfma<64, true, false><<<gb, 256, 0, stream>>>(bufB, wp3, dinv, bufA, NN);
    k_agg_softmax<<<ab4, 256, 0, stream>>>((uint2*)bufA, offs, deg, srcs, dinv, b3, (float4*)outp, NN);
}